// Round 3
// baseline (3282.252 us; speedup 1.0000x reference)
//
#include <hip/hip_runtime.h>
#include <math.h>

#define S 2048
#define D 1024
#define NH 16
#define HD 32
#define HD2 64

static constexpr float SCALE_Q       = 0.17677669529663687f;   // 32^-0.5
static constexpr float LAMBDA_INIT_F = 0.78360576653162450f;   // 0.8 - 0.6*exp(-3.6)
static constexpr float ONE_MINUS_LI  = 0.21639423346837553f;

// ---------------- prep: trig tables (bit-matching the f32 numpy/jax pipeline) ----------------
// Reference: p = powf(f32(1e-4), m/16)  [correctly-rounded f32 pow -> small value],
//            freq = 1.0f / p            [second f32 rounding],
//            ang  = f32(pos) * freq     [f32 multiply],
//            cos/sin = correctly-rounded f32 trig of that exact f32 angle.
// We reproduce each rounding step exactly; trig via double of the f32 angle == CR f32 trig.
__global__ void prep_kernel(const float* __restrict__ lq1, const float* __restrict__ lk1,
                            const float* __restrict__ lq2, const float* __restrict__ lk2,
                            float* __restrict__ cosT, float* __restrict__ sinT,
                            float* __restrict__ lamOut) {
    int idx = blockIdx.x * blockDim.x + threadIdx.x;
    if (idx < S * 16) {
        int p = idx >> 4;
        int m = idx & 15;
        const double base = (double)1.0e-4f;            // f32-rounded THETA, as numpy casts it
        float pf   = (float)pow(base, (double)m * (1.0 / 16.0));  // == powf(1e-4f, m/16), CR
        float freq = 1.0f / pf;                          // f32 division, matches 1.0/(THETA**e)
        float angf = (float)p * freq;                    // bit-exact f32 multiply
        double a = (double)angf;
        cosT[idx] = (float)cos(a);
        sinT[idx] = (float)sin(a);
    }
    if (blockIdx.x == 0 && threadIdx.x == 0) {
        float s1 = 0.f, s2 = 0.f;
        for (int i = 0; i < HD; ++i) {
            s1 += lq1[i] * lk1[i];
            s2 += lq2[i] * lk2[i];
        }
        *lamOut = expf(s1) - expf(s2) + LAMBDA_INIT_F;
    }
}

// ---------------- fp32 tiled GEMM, 64x64 tile, BK=16 ----------------
// MODE 0: Q = x@Wq, fused RoPE + scale, write head-major (32,S,32)
// MODE 1: K = x@Wk, fused RoPE,          write head-major (32,S,32)
// MODE 2: V = x@Wv,                      write head-major (16,S,64)
// MODE 3: out = attn@Wo,                 write row-major (S,D)
template<int MODE>
__global__ __launch_bounds__(256)
void gemm_kernel(const float* __restrict__ X, const float* __restrict__ W,
                 const float* __restrict__ cosT, const float* __restrict__ sinT,
                 float* __restrict__ Out) {
    __shared__ __align__(16) float XsT[16][68];  // transposed X tile [k][row]
    __shared__ __align__(16) float Ws[16][68];   // W tile [k][col]
    const int bx = blockIdx.x, by = blockIdx.y;
    const int tid = threadIdx.x;
    const int tx = tid & 15, ty = tid >> 4;
    const int row0 = by * 64, col0 = bx * 64;

    float acc[4][4] = {};

    for (int kk = 0; kk < D; kk += 16) {
        {   // X tile: 64 rows x 16 cols, stored transposed
            int r = tid >> 2, c = (tid & 3) << 2;
            const float4 v = *(const float4*)&X[(size_t)(row0 + r) * D + kk + c];
            XsT[c + 0][r] = v.x; XsT[c + 1][r] = v.y;
            XsT[c + 2][r] = v.z; XsT[c + 3][r] = v.w;
        }
        {   // W tile: 16 rows x 64 cols
            int r = tid >> 4, c = (tid & 15) << 2;
            *(float4*)&Ws[r][c] = *(const float4*)&W[(size_t)(kk + r) * D + col0 + c];
        }
        __syncthreads();
#pragma unroll
        for (int k = 0; k < 16; ++k) {
            const float4 a = *(const float4*)&XsT[k][ty << 2];
            const float4 b = *(const float4*)&Ws[k][tx << 2];
            const float av[4] = {a.x, a.y, a.z, a.w};
            const float bv[4] = {b.x, b.y, b.z, b.w};
#pragma unroll
            for (int i = 0; i < 4; ++i)
#pragma unroll
                for (int j = 0; j < 4; ++j)
                    acc[i][j] = fmaf(av[i], bv[j], acc[i][j]);
        }
        __syncthreads();
    }

    const int c0 = col0 + (tx << 2);
#pragma unroll
    for (int i = 0; i < 4; ++i) {
        const int row = row0 + (ty << 2) + i;
        if (MODE == 0 || MODE == 1) {
            const int head = c0 >> 5;
            const int d0 = c0 & 31;
            const int m0 = d0 >> 1;             // pairs m0, m0+1
            const float cA = cosT[(row << 4) + m0],     sA = sinT[(row << 4) + m0];
            const float cB = cosT[(row << 4) + m0 + 1], sB = sinT[(row << 4) + m0 + 1];
            float o0 = acc[i][0] * cA - acc[i][1] * sA;
            float o1 = acc[i][0] * sA + acc[i][1] * cA;
            float o2 = acc[i][2] * cB - acc[i][3] * sB;
            float o3 = acc[i][2] * sB + acc[i][3] * cB;
            if (MODE == 0) { o0 *= SCALE_Q; o1 *= SCALE_Q; o2 *= SCALE_Q; o3 *= SCALE_Q; }
            float4 res = make_float4(o0, o1, o2, o3);
            *(float4*)&Out[((size_t)head * S + row) * HD + d0] = res;
        } else if (MODE == 2) {
            const int head = c0 >> 6;
            const int d0 = c0 & 63;
            float4 res = make_float4(acc[i][0], acc[i][1], acc[i][2], acc[i][3]);
            *(float4*)&Out[((size_t)head * S + row) * HD2 + d0] = res;
        } else {
            float4 res = make_float4(acc[i][0], acc[i][1], acc[i][2], acc[i][3]);
            *(float4*)&Out[(size_t)row * D + c0] = res;
        }
    }
}

// ---------------- helpers: reductions within 16-lane groups ----------------
__device__ __forceinline__ float grp_max16(float v) {
#pragma unroll
    for (int o = 1; o < 16; o <<= 1) v = fmaxf(v, __shfl_xor(v, o, 16));
    return v;
}
__device__ __forceinline__ float grp_sum16(float v) {
#pragma unroll
    for (int o = 1; o < 16; o <<= 1) v += __shfl_xor(v, o, 16);
    return v;
}

// ---------------- differential flash attention (fp32) ----------------
// grid: (S/16, NH); block 256 = 16 rows x 16 lanes
__global__ __launch_bounds__(256)
void attn_kernel(const float* __restrict__ Qh, const float* __restrict__ Kh,
                 const float* __restrict__ Vh, const float* __restrict__ lamPtr,
                 const float* __restrict__ g, float* __restrict__ AO) {
    const int h = blockIdx.y;
    const int p0 = blockIdx.x << 4;
    const int tid = threadIdx.x;
    const int r = tid >> 4;          // 0..15 row in tile
    const int gi = tid & 15;         // 0..15 lane in row-group
    const int d4 = gi << 2;          // 4 output dims owned

    __shared__ __align__(16) float q1s[16][36], q2s[16][36];
    __shared__ __align__(16) float e1s[16][68], e2s[16][68];

    const float lam = *lamPtr;

    for (int i = tid; i < 16 * 32; i += 256) {
        int rr = i >> 5, d = i & 31;
        q1s[rr][d] = Qh[((size_t)(2 * h) * S + p0 + rr) * HD + d];
        q2s[rr][d] = Qh[((size_t)(2 * h + 1) * S + p0 + rr) * HD + d];
    }
    __syncthreads();

    float m1 = -INFINITY, m2 = -INFINITY, l1 = 0.f, l2 = 0.f;
    float acc1[4] = {0.f, 0.f, 0.f, 0.f}, acc2[4] = {0.f, 0.f, 0.f, 0.f};

    const float* Kbase1 = Kh + (size_t)(2 * h) * S * HD;
    const float* Kbase2 = Kbase1 + (size_t)S * HD;
    const float* Vbase  = Vh + (size_t)h * S * HD2;

    for (int k0 = 0; k0 < S; k0 += 64) {
        float sc1[4], sc2[4];
#pragma unroll
        for (int j = 0; j < 4; ++j) {
            const int k = k0 + (gi << 2) + j;
            const float* kp1 = Kbase1 + (size_t)k * HD;
            const float* kp2 = Kbase2 + (size_t)k * HD;
            float s1 = 0.f, s2 = 0.f;
#pragma unroll
            for (int d = 0; d < 32; d += 4) {
                const float4 a1 = *(const float4*)(kp1 + d);
                const float4 a2 = *(const float4*)(kp2 + d);
                const float4 q1 = *(const float4*)&q1s[r][d];
                const float4 q2 = *(const float4*)&q2s[r][d];
                s1 += q1.x * a1.x + q1.y * a1.y + q1.z * a1.z + q1.w * a1.w;
                s2 += q2.x * a2.x + q2.y * a2.y + q2.z * a2.z + q2.w * a2.w;
            }
            sc1[j] = s1; sc2[j] = s2;
        }
        // online softmax update (two heads)
        float lm1 = fmaxf(fmaxf(sc1[0], sc1[1]), fmaxf(sc1[2], sc1[3]));
        float lm2 = fmaxf(fmaxf(sc2[0], sc2[1]), fmaxf(sc2[2], sc2[3]));
        const float M1 = grp_max16(lm1), M2 = grp_max16(lm2);
        const float m1n = fmaxf(m1, M1), m2n = fmaxf(m2, M2);
        const float f1 = expf(m1 - m1n), f2 = expf(m2 - m2n);
        float ls1 = 0.f, ls2 = 0.f;
#pragma unroll
        for (int j = 0; j < 4; ++j) {
            const float e1 = expf(sc1[j] - m1n);
            const float e2 = expf(sc2[j] - m2n);
            e1s[r][(gi << 2) + j] = e1;
            e2s[r][(gi << 2) + j] = e2;
            ls1 += e1; ls2 += e2;
        }
        l1 = l1 * f1 + grp_sum16(ls1);
        l2 = l2 * f2 + grp_sum16(ls2);
        m1 = m1n; m2 = m2n;
        __syncthreads();

#pragma unroll
        for (int j = 0; j < 4; ++j) { acc1[j] *= f1; acc2[j] *= f2; }
        const float* vp = Vbase + (size_t)k0 * HD2 + d4;
        for (int kc = 0; kc < 64; ++kc) {
            const float4 v = *(const float4*)(vp + (size_t)kc * HD2);
            const float w1 = e1s[r][kc], w2 = e2s[r][kc];
            acc1[0] = fmaf(w1, v.x, acc1[0]); acc2[0] = fmaf(w2, v.x, acc2[0]);
            acc1[1] = fmaf(w1, v.y, acc1[1]); acc2[1] = fmaf(w2, v.y, acc2[1]);
            acc1[2] = fmaf(w1, v.z, acc1[2]); acc2[2] = fmaf(w2, v.z, acc2[2]);
            acc1[3] = fmaf(w1, v.w, acc1[3]); acc2[3] = fmaf(w2, v.w, acc2[3]);
        }
        __syncthreads();
    }

    // finalize: attn = acc1/l1 - lam*acc2/l2; RMS over 64 dims; *g*(1-li)
    const float inv1 = 1.0f / l1, inv2 = 1.0f / l2;
    float o[4];
#pragma unroll
    for (int j = 0; j < 4; ++j) o[j] = acc1[j] * inv1 - lam * (acc2[j] * inv2);
    float ss = o[0] * o[0] + o[1] * o[1] + o[2] * o[2] + o[3] * o[3];
    const float SS = grp_sum16(ss);
    const float rms = 1.0f / sqrtf(SS * (1.0f / 64.0f) + 1e-5f);
    float4 res;
    res.x = o[0] * rms * g[d4 + 0] * ONE_MINUS_LI;
    res.y = o[1] * rms * g[d4 + 1] * ONE_MINUS_LI;
    res.z = o[2] * rms * g[d4 + 2] * ONE_MINUS_LI;
    res.w = o[3] * rms * g[d4 + 3] * ONE_MINUS_LI;
    *(float4*)&AO[(size_t)(p0 + r) * D + (h << 6) + d4] = res;
}

// ---------------- launch ----------------
extern "C" void kernel_launch(void* const* d_in, const int* in_sizes, int n_in,
                              void* d_out, int out_size, void* d_ws, size_t ws_size,
                              hipStream_t stream) {
    const float* x   = (const float*)d_in[0];
    const float* Wq  = (const float*)d_in[1];
    const float* Wk  = (const float*)d_in[2];
    const float* Wv  = (const float*)d_in[3];
    const float* Wo  = (const float*)d_in[4];
    const float* lq1 = (const float*)d_in[5];
    const float* lk1 = (const float*)d_in[6];
    const float* lq2 = (const float*)d_in[7];
    const float* lk2 = (const float*)d_in[8];
    const float* g   = (const float*)d_in[9];
    float* out = (float*)d_out;

    char* ws = (char*)d_ws;
    float* cosT = (float*)(ws);
    float* sinT = (float*)(ws + 131072);
    float* lam  = (float*)(ws + 262144);
    float* Qh   = (float*)(ws + 262400);                       // 32*2048*32 f32 = 8 MB
    float* Kh   = (float*)(ws + 262400 + 8388608);             // 8 MB
    float* Vh   = (float*)(ws + 262400 + 2 * 8388608);         // 8 MB
    float* AO   = (float*)(ws + 262400 + 3 * 8388608);         // 8 MB

    prep_kernel<<<128, 256, 0, stream>>>(lq1, lk1, lq2, lk2, cosT, sinT, lam);

    dim3 gg(D / 64, S / 64);
    gemm_kernel<0><<<gg, 256, 0, stream>>>(x, Wq, cosT, sinT, Qh);
    gemm_kernel<1><<<gg, 256, 0, stream>>>(x, Wk, cosT, sinT, Kh);
    gemm_kernel<2><<<gg, 256, 0, stream>>>(x, Wv, nullptr, nullptr, Vh);

    attn_kernel<<<dim3(S / 16, NH), 256, 0, stream>>>(Qh, Kh, Vh, lam, g, AO);

    gemm_kernel<3><<<gg, 256, 0, stream>>>(AO, Wo, nullptr, nullptr, out);
}

// Round 4
// 320.722 us; speedup vs baseline: 10.2340x; 10.2340x over previous
//
#include <hip/hip_runtime.h>
#include <math.h>

#define S 2048
#define D 1024
#define NH 16
#define HD 32
#define HD2 64

static constexpr float SCALE_Q       = 0.17677669529663687f;   // 32^-0.5
static constexpr float LAMBDA_INIT_F = 0.78360576653162450f;   // 0.8 - 0.6*exp(-3.6)
static constexpr float ONE_MINUS_LI  = 0.21639423346837553f;

typedef unsigned short u16;
typedef unsigned int   u32;
typedef __attribute__((ext_vector_type(4)))  unsigned short u16x4;
typedef __attribute__((ext_vector_type(8)))  short          bfrag;   // 8 bf16 = 4 VGPR
typedef __attribute__((ext_vector_type(16))) float          f16acc;  // MFMA 32x32 accumulator
typedef __attribute__((ext_vector_type(4)))  unsigned int   uint4v;

__device__ __forceinline__ u16 f2bf(float f) {                 // RNE f32->bf16
    u32 u = __builtin_bit_cast(u32, f);
    return (u16)((u + 0x7FFFu + ((u >> 16) & 1u)) >> 16);
}
__device__ __forceinline__ f16acc zero16() {
    f16acc z;
#pragma unroll
    for (int i = 0; i < 16; ++i) z[i] = 0.f;
    return z;
}
#define MFMA(a, b, c) __builtin_amdgcn_mfma_f32_32x32x16_bf16(a, b, c, 0, 0, 0)

// ---------------- prep: trig tables (bit-matching the f32 numpy/jax pipeline) ----------------
__global__ void prep_kernel(const float* __restrict__ lq1, const float* __restrict__ lk1,
                            const float* __restrict__ lq2, const float* __restrict__ lk2,
                            float* __restrict__ cosT, float* __restrict__ sinT,
                            float* __restrict__ lamOut) {
    int idx = blockIdx.x * blockDim.x + threadIdx.x;
    if (idx < S * 16) {
        int p = idx >> 4;
        int m = idx & 15;
        const double base = (double)1.0e-4f;
        float pf   = (float)pow(base, (double)m * (1.0 / 16.0));  // == powf(1e-4f, m/16), CR
        float freq = 1.0f / pf;                                   // f32 division
        float angf = (float)p * freq;                             // exact f32 multiply
        double a = (double)angf;
        cosT[idx] = (float)cos(a);
        sinT[idx] = (float)sin(a);
    }
    if (blockIdx.x == 0 && threadIdx.x == 0) {
        float s1 = 0.f, s2 = 0.f;
        for (int i = 0; i < HD; ++i) {
            s1 += lq1[i] * lk1[i];
            s2 += lq2[i] * lk2[i];
        }
        *lamOut = expf(s1) - expf(s2) + LAMBDA_INIT_F;
    }
}

// ---------------- fp32 tiled GEMM, 64x64 tile, BK=16 ----------------
// MODE 0: Q = x@Wq, RoPE+scale, bf16 head-major [32][S][32]
// MODE 1: K = x@Wk, RoPE,       bf16 head-major [32][S][32]
// MODE 2: V = x@Wv,             bf16 V-TRANSPOSED [16 heads][64 d][S]
// MODE 3: out = attn@Wo,        f32 row-major [S][D]
template<int MODE>
__global__ __launch_bounds__(256)
void gemm_kernel(const float* __restrict__ X, const float* __restrict__ W,
                 const float* __restrict__ cosT, const float* __restrict__ sinT,
                 void* __restrict__ Out) {
    __shared__ __align__(16) float XsT[16][68];
    __shared__ __align__(16) float Ws[16][68];
    const int bx = blockIdx.x, by = blockIdx.y;
    const int tid = threadIdx.x;
    const int tx = tid & 15, ty = tid >> 4;
    const int row0 = by * 64, col0 = bx * 64;

    float acc[4][4] = {};

    for (int kk = 0; kk < D; kk += 16) {
        {
            int r = tid >> 2, c = (tid & 3) << 2;
            const float4 v = *(const float4*)&X[(size_t)(row0 + r) * D + kk + c];
            XsT[c + 0][r] = v.x; XsT[c + 1][r] = v.y;
            XsT[c + 2][r] = v.z; XsT[c + 3][r] = v.w;
        }
        {
            int r = tid >> 4, c = (tid & 15) << 2;
            *(float4*)&Ws[r][c] = *(const float4*)&W[(size_t)(kk + r) * D + col0 + c];
        }
        __syncthreads();
#pragma unroll
        for (int k = 0; k < 16; ++k) {
            const float4 a = *(const float4*)&XsT[k][ty << 2];
            const float4 b = *(const float4*)&Ws[k][tx << 2];
            const float av[4] = {a.x, a.y, a.z, a.w};
            const float bv[4] = {b.x, b.y, b.z, b.w};
#pragma unroll
            for (int i = 0; i < 4; ++i)
#pragma unroll
                for (int j = 0; j < 4; ++j)
                    acc[i][j] = fmaf(av[i], bv[j], acc[i][j]);
        }
        __syncthreads();
    }

    const int c0 = col0 + (tx << 2);
    if (MODE == 0 || MODE == 1) {
        u16* Ob = (u16*)Out;
#pragma unroll
        for (int i = 0; i < 4; ++i) {
            const int row = row0 + (ty << 2) + i;
            const int head = c0 >> 5;
            const int d0 = c0 & 31;
            const int m0 = d0 >> 1;
            const float cA = cosT[(row << 4) + m0],     sA = sinT[(row << 4) + m0];
            const float cB = cosT[(row << 4) + m0 + 1], sB = sinT[(row << 4) + m0 + 1];
            float o0 = acc[i][0] * cA - acc[i][1] * sA;
            float o1 = acc[i][0] * sA + acc[i][1] * cA;
            float o2 = acc[i][2] * cB - acc[i][3] * sB;
            float o3 = acc[i][2] * sB + acc[i][3] * cB;
            if (MODE == 0) { o0 *= SCALE_Q; o1 *= SCALE_Q; o2 *= SCALE_Q; o3 *= SCALE_Q; }
            u16x4 res; res.x = f2bf(o0); res.y = f2bf(o1); res.z = f2bf(o2); res.w = f2bf(o3);
            *(u16x4*)&Ob[((size_t)head * S + row) * HD + d0] = res;
        }
    } else if (MODE == 2) {
        u16* Ob = (u16*)Out;
#pragma unroll
        for (int j = 0; j < 4; ++j) {   // V^T: [global col][s], 4 consecutive s rows
            u16x4 res;
            res.x = f2bf(acc[0][j]); res.y = f2bf(acc[1][j]);
            res.z = f2bf(acc[2][j]); res.w = f2bf(acc[3][j]);
            *(u16x4*)&Ob[(size_t)(c0 + j) * S + row0 + (ty << 2)] = res;
        }
    } else {
        float* Of = (float*)Out;
#pragma unroll
        for (int i = 0; i < 4; ++i) {
            const int row = row0 + (ty << 2) + i;
            float4 res = make_float4(acc[i][0], acc[i][1], acc[i][2], acc[i][3]);
            *(float4*)&Of[(size_t)row * D + c0] = res;
        }
    }
}

// ---------------- MFMA differential flash attention ----------------
// grid (16 qgroups, 16 heads), 256 thr = 4 waves; wave = one 32-q tile, both sub-heads.
// Register-only: no LDS, no barriers. Swapped QK^T -> per-lane q-column softmax;
// P redistributed to B-frag layout via cvt_pk_bf16 + permlane32_swap; O^T = V^T * P^T.
__global__ __launch_bounds__(256)
void attn_mfma(const u16* __restrict__ Qb, const u16* __restrict__ Kb,
               const u16* __restrict__ Vt, const float* __restrict__ lamPtr,
               const float* __restrict__ g, float* __restrict__ AO) {
    const int h    = blockIdx.y;
    const int tid  = threadIdx.x;
    const int wave = tid >> 6;
    const int lane = tid & 63;
    const int hi   = lane >> 5;
    const int ql   = lane & 31;
    const int q0   = (blockIdx.x * 4 + wave) * 32;
    const float lam = *lamPtr;

    // persistent Q fragments (B-operand): Q[q0+ql][16s + 8hi + 0..7]
    const u16* qp1 = Qb + ((size_t)(2 * h) * S + q0 + ql) * HD + 8 * hi;
    const u16* qp2 = qp1 + (size_t)S * HD;
    bfrag qf1[2], qf2[2];
    qf1[0] = *(const bfrag*)(qp1);      qf1[1] = *(const bfrag*)(qp1 + 16);
    qf2[0] = *(const bfrag*)(qp2);      qf2[1] = *(const bfrag*)(qp2 + 16);

    const u16* kp1 = Kb + ((size_t)(2 * h) * S + ql) * HD + 8 * hi;  // + c*1024 + 16s
    const u16* kp2 = kp1 + (size_t)S * HD;
    const u16* vp  = Vt + ((size_t)(h * 64) + ql) * S + 8 * hi;      // + dt*32*S + c*32 + 16s

    f16acc acc1[2], acc2[2];
    acc1[0] = zero16(); acc1[1] = zero16();
    acc2[0] = zero16(); acc2[1] = zero16();
    float m1 = -3.0e38f, m2 = -3.0e38f, l1 = 0.f, l2 = 0.f;

    // prefetch chunk 0
    bfrag k1c[2], k2c[2], vc[2][2];
#pragma unroll
    for (int s = 0; s < 2; ++s) {
        k1c[s] = *(const bfrag*)(kp1 + 16 * s);
        k2c[s] = *(const bfrag*)(kp2 + 16 * s);
#pragma unroll
        for (int dt = 0; dt < 2; ++dt)
            vc[s][dt] = *(const bfrag*)(vp + (size_t)dt * 32 * S + 16 * s);
    }

    for (int c = 0; c < 64; ++c) {
        // ---- issue next chunk's loads (register double-buffer) ----
        const int cn = (c < 63) ? c + 1 : c;
        bfrag k1n[2], k2n[2], vn[2][2];
#pragma unroll
        for (int s = 0; s < 2; ++s) {
            k1n[s] = *(const bfrag*)(kp1 + (size_t)cn * 1024 + 16 * s);
            k2n[s] = *(const bfrag*)(kp2 + (size_t)cn * 1024 + 16 * s);
#pragma unroll
            for (int dt = 0; dt < 2; ++dt)
                vn[s][dt] = *(const bfrag*)(vp + (size_t)dt * 32 * S + (size_t)cn * 32 + 16 * s);
        }

        // ---- scores: D[k][q] = K . Q (swapped) ----
        f16acc s1 = zero16(), s2 = zero16();
        s1 = MFMA(k1c[0], qf1[0], s1);  s1 = MFMA(k1c[1], qf1[1], s1);
        s2 = MFMA(k2c[0], qf2[0], s2);  s2 = MFMA(k2c[1], qf2[1], s2);

        // ---- online softmax (per-lane = one q-column; partner lane^32 has other 16 k) ----
        float cm1 = s1[0], cm2 = s2[0];
#pragma unroll
        for (int r = 1; r < 16; ++r) { cm1 = fmaxf(cm1, s1[r]); cm2 = fmaxf(cm2, s2[r]); }
        cm1 = fmaxf(cm1, __shfl_xor(cm1, 32));
        cm2 = fmaxf(cm2, __shfl_xor(cm2, 32));
        if (__any((cm1 > m1 + 8.f) || (cm2 > m2 + 8.f))) {   // defer-rescale (T13)
            float nm1 = fmaxf(m1, cm1), nm2 = fmaxf(m2, cm2);
            float f1 = __expf(m1 - nm1), f2 = __expf(m2 - nm2);
#pragma unroll
            for (int dt = 0; dt < 2; ++dt)
#pragma unroll
                for (int r = 0; r < 16; ++r) { acc1[dt][r] *= f1; acc2[dt][r] *= f2; }
            l1 *= f1; l2 *= f2; m1 = nm1; m2 = nm2;
        }
        float e1[16], e2[16];
        float ls1 = 0.f, ls2 = 0.f;
#pragma unroll
        for (int r = 0; r < 16; ++r) {
            e1[r] = __expf(s1[r] - m1); ls1 += e1[r];
            e2[r] = __expf(s2[r] - m2); ls2 += e2[r];
        }
        ls1 += __shfl_xor(ls1, 32);
        ls2 += __shfl_xor(ls2, 32);
        l1 += ls1; l2 += ls2;

        // ---- P -> bf16 B-fragments: cvt_pk pairs, then permlane32_swap (T12) ----
        u32 w1[8], w2[8];
#pragma unroll
        for (int j = 0; j < 8; ++j) {
            asm("v_cvt_pk_bf16_f32 %0, %1, %2" : "=v"(w1[j]) : "v"(e1[2 * j]), "v"(e1[2 * j + 1]));
            asm("v_cvt_pk_bf16_f32 %0, %1, %2" : "=v"(w2[j]) : "v"(e2[2 * j]), "v"(e2[2 * j + 1]));
        }
        asm("v_permlane32_swap_b32 %0, %1" : "+v"(w1[0]), "+v"(w1[2]));
        asm("v_permlane32_swap_b32 %0, %1" : "+v"(w1[1]), "+v"(w1[3]));
        asm("v_permlane32_swap_b32 %0, %1" : "+v"(w1[4]), "+v"(w1[6]));
        asm("v_permlane32_swap_b32 %0, %1" : "+v"(w1[5]), "+v"(w1[7]));
        asm("v_permlane32_swap_b32 %0, %1" : "+v"(w2[0]), "+v"(w2[2]));
        asm("v_permlane32_swap_b32 %0, %1" : "+v"(w2[1]), "+v"(w2[3]));
        asm("v_permlane32_swap_b32 %0, %1" : "+v"(w2[4]), "+v"(w2[6]));
        asm("v_permlane32_swap_b32 %0, %1" : "+v"(w2[5]), "+v"(w2[7]));
        uint4v t;
        bfrag p1[2], p2[2];
        t[0] = w1[0]; t[1] = w1[1]; t[2] = w1[2]; t[3] = w1[3];
        p1[0] = __builtin_bit_cast(bfrag, t);
        t[0] = w1[4]; t[1] = w1[5]; t[2] = w1[6]; t[3] = w1[7];
        p1[1] = __builtin_bit_cast(bfrag, t);
        t[0] = w2[0]; t[1] = w2[1]; t[2] = w2[2]; t[3] = w2[3];
        p2[0] = __builtin_bit_cast(bfrag, t);
        t[0] = w2[4]; t[1] = w2[5]; t[2] = w2[6]; t[3] = w2[7];
        p2[1] = __builtin_bit_cast(bfrag, t);

        // ---- PV: O^T[d][q] += V^T . P^T ----
#pragma unroll
        for (int dt = 0; dt < 2; ++dt) {
            acc1[dt] = MFMA(vc[0][dt], p1[0], acc1[dt]);
            acc1[dt] = MFMA(vc[1][dt], p1[1], acc1[dt]);
            acc2[dt] = MFMA(vc[0][dt], p2[0], acc2[dt]);
            acc2[dt] = MFMA(vc[1][dt], p2[1], acc2[dt]);
        }

        // rotate buffers
#pragma unroll
        for (int s = 0; s < 2; ++s) {
            k1c[s] = k1n[s]; k2c[s] = k2n[s];
#pragma unroll
            for (int dt = 0; dt < 2; ++dt) vc[s][dt] = vn[s][dt];
        }
    }

    // ---- epilogue: diff, RMS over 64 dims, *g*(1-lambda_init), store f32 ----
    const float inv1 = 1.0f / l1, inv2 = 1.0f / l2;
    float o_[2][16];
    float ss = 0.f;
#pragma unroll
    for (int dt = 0; dt < 2; ++dt)
#pragma unroll
        for (int r = 0; r < 16; ++r) {
            float o = acc1[dt][r] * inv1 - lam * (acc2[dt][r] * inv2);
            o_[dt][r] = o;
            ss += o * o;
        }
    ss += __shfl_xor(ss, 32);
    const float rs = rsqrtf(ss * (1.0f / 64.0f) + 1e-5f);

    float* aorow = AO + (size_t)(q0 + ql) * D + h * 64;
#pragma unroll
    for (int dt = 0; dt < 2; ++dt)
#pragma unroll
        for (int G = 0; G < 4; ++G) {
            const int dbase = dt * 32 + G * 8 + hi * 4;
            const float4 gv = *(const float4*)&g[dbase];
            float4 res;
            res.x = o_[dt][4 * G + 0] * rs * gv.x * ONE_MINUS_LI;
            res.y = o_[dt][4 * G + 1] * rs * gv.y * ONE_MINUS_LI;
            res.z = o_[dt][4 * G + 2] * rs * gv.z * ONE_MINUS_LI;
            res.w = o_[dt][4 * G + 3] * rs * gv.w * ONE_MINUS_LI;
            *(float4*)&aorow[dbase] = res;
        }
}

// ---------------- launch ----------------
extern "C" void kernel_launch(void* const* d_in, const int* in_sizes, int n_in,
                              void* d_out, int out_size, void* d_ws, size_t ws_size,
                              hipStream_t stream) {
    const float* x   = (const float*)d_in[0];
    const float* Wq  = (const float*)d_in[1];
    const float* Wk  = (const float*)d_in[2];
    const float* Wv  = (const float*)d_in[3];
    const float* Wo  = (const float*)d_in[4];
    const float* lq1 = (const float*)d_in[5];
    const float* lk1 = (const float*)d_in[6];
    const float* lq2 = (const float*)d_in[7];
    const float* lk2 = (const float*)d_in[8];
    const float* g   = (const float*)d_in[9];
    float* out = (float*)d_out;

    char* ws = (char*)d_ws;
    float* cosT = (float*)(ws);                       // 128 KB
    float* sinT = (float*)(ws + 131072);              // 128 KB
    float* lam  = (float*)(ws + 262144);              // 256 B
    u16*   Qbf  = (u16*)(ws + 262400);                // 32*2048*32 bf16 = 4 MB
    u16*   Kbf  = (u16*)(ws + 262400 + 4194304);      // 4 MB
    u16*   VT   = (u16*)(ws + 262400 + 2 * 4194304);  // 16*64*2048 bf16 = 4 MB
    float* AO   = (float*)(ws + 262400 + 3 * 4194304);// 8 MB

    prep_kernel<<<128, 256, 0, stream>>>(lq1, lk1, lq2, lk2, cosT, sinT, lam);

    dim3 gg(D / 64, S / 64);
    gemm_kernel<0><<<gg, 256, 0, stream>>>(x, Wq, cosT, sinT, (void*)Qbf);
    gemm_kernel<1><<<gg, 256, 0, stream>>>(x, Wk, cosT, sinT, (void*)Kbf);
    gemm_kernel<2><<<gg, 256, 0, stream>>>(x, Wv, nullptr, nullptr, (void*)VT);

    attn_mfma<<<dim3(16, NH), 256, 0, stream>>>(Qbf, Kbf, VT, lam, g, AO);

    gemm_kernel<3><<<gg, 256, 0, stream>>>(AO, Wo, nullptr, nullptr, (void*)out);
}

// Round 5
// 152.255 us; speedup vs baseline: 21.5576x; 2.1065x over previous
//
#include <hip/hip_runtime.h>
#include <math.h>

#define S 2048
#define D 1024
#define NH 16
#define HD 32
#define HD2 64

static constexpr float SCALE_Q       = 0.17677669529663687f;   // 32^-0.5
static constexpr float LAMBDA_INIT_F = 0.78360576653162450f;   // 0.8 - 0.6*exp(-3.6)
static constexpr float ONE_MINUS_LI  = 0.21639423346837553f;

typedef unsigned short u16;
typedef unsigned int   u32;
typedef __attribute__((ext_vector_type(4)))  unsigned short u16x4;
typedef __attribute__((ext_vector_type(8)))  short          bfrag;   // 8 bf16 = 4 VGPR
typedef __attribute__((ext_vector_type(16))) float          f16acc;  // MFMA 32x32 accumulator
typedef __attribute__((ext_vector_type(4)))  unsigned int   uint4v;

__device__ __forceinline__ u16 f2bf(float f) {                 // RNE f32->bf16
    u32 u = __builtin_bit_cast(u32, f);
    return (u16)((u + 0x7FFFu + ((u >> 16) & 1u)) >> 16);
}
__device__ __forceinline__ f16acc zero16() {
    f16acc z;
#pragma unroll
    for (int i = 0; i < 16; ++i) z[i] = 0.f;
    return z;
}
#define MFMA(a, b, c) __builtin_amdgcn_mfma_f32_32x32x16_bf16(a, b, c, 0, 0, 0)

__device__ __forceinline__ void gload16(const u16* src, u16* lds) {
    __builtin_amdgcn_global_load_lds((const __attribute__((address_space(1))) void*)src,
                                     (__attribute__((address_space(3))) void*)lds, 16, 0, 0);
}

// ---------------- prep: trig tables (bit-matching the f32 numpy/jax pipeline) ----------------
__global__ void prep_kernel(const float* __restrict__ lq1, const float* __restrict__ lk1,
                            const float* __restrict__ lq2, const float* __restrict__ lk2,
                            float* __restrict__ cosT, float* __restrict__ sinT,
                            float* __restrict__ lamOut) {
    int idx = blockIdx.x * blockDim.x + threadIdx.x;
    if (idx < S * 16) {
        int p = idx >> 4;
        int m = idx & 15;
        const double base = (double)1.0e-4f;
        float pf   = (float)pow(base, (double)m * (1.0 / 16.0));  // == powf(1e-4f, m/16), CR
        float freq = 1.0f / pf;                                   // f32 division
        float angf = (float)p * freq;                             // exact f32 multiply
        double a = (double)angf;
        cosT[idx] = (float)cos(a);
        sinT[idx] = (float)sin(a);
    }
    if (blockIdx.x == 0 && threadIdx.x == 0) {
        float s1 = 0.f, s2 = 0.f;
        for (int i = 0; i < HD; ++i) {
            s1 += lq1[i] * lk1[i];
            s2 += lq2[i] * lk2[i];
        }
        *lamOut = expf(s1) - expf(s2) + LAMBDA_INIT_F;
    }
}

// ---------------- convert: x -> bf16; W -> bf16 transposed [n][k] ----------------
__global__ __launch_bounds__(256)
void convert_kernel(const float* __restrict__ x,  const float* __restrict__ Wq,
                    const float* __restrict__ Wk, const float* __restrict__ Wv,
                    const float* __restrict__ Wo,
                    u16* __restrict__ xb,  u16* __restrict__ WqT, u16* __restrict__ WkT,
                    u16* __restrict__ WvT, u16* __restrict__ WoT) {
    const int z = blockIdx.y;
    const int i = blockIdx.x * 256 + threadIdx.x;
    if (z == 0) {
        if (i < (S * D) / 4) {
            const float4 v = *(const float4*)&x[(size_t)i * 4];
            u16x4 r; r.x = f2bf(v.x); r.y = f2bf(v.y); r.z = f2bf(v.z); r.w = f2bf(v.w);
            *(u16x4*)&xb[(size_t)i * 4] = r;
        }
    } else {
        if (i < D * D) {
            const int k = i >> 10, n = i & 1023;
            const float* W = (z == 1) ? Wq : (z == 2) ? Wk : (z == 3) ? Wv : Wo;
            u16* T = (z == 1) ? WqT : (z == 2) ? WkT : (z == 3) ? WvT : WoT;
            T[(size_t)n * D + k] = f2bf(W[i]);
        }
    }
}

// ---------------- bf16 MFMA GEMM, 128x128 tile, BK=32, 4 waves (m97 structure) ----------------
// MODE 0: fused QKV (A=xb, B in {WqT,WkT,WvT} by blockIdx.x/8); epilogue RoPE->Qb/Kb, V^T->VT
// MODE 1: O-proj (A=AO bf16, B=WoT); epilogue f32 row-major to d_out
template<int MODE>
__global__ __launch_bounds__(256)
void mm_kernel(const u16* __restrict__ Ab, const u16* __restrict__ B0,
               const u16* __restrict__ B1, const u16* __restrict__ B2,
               const float* __restrict__ cosT, const float* __restrict__ sinT,
               u16* __restrict__ Qb, u16* __restrict__ Kb, u16* __restrict__ VT,
               float* __restrict__ Of) {
    __shared__ u16 As[128 * 32];
    __shared__ u16 Bs[128 * 32];

    const int nb   = blockIdx.x;
    const int row0 = blockIdx.y * 128;
    const int tid  = threadIdx.x;
    const int wave = tid >> 6;
    const int lane = tid & 63;
    const int ql   = lane & 31;
    const int hi   = lane >> 5;
    const int wr   = wave >> 1;     // 0,1 -> row half
    const int wc   = wave & 1;      // 0,1 -> col half

    const u16* Bt;
    int col0B;
    if (MODE == 0) {
        Bt = (nb < 8) ? B0 : (nb < 16) ? B1 : B2;
        col0B = (nb & 7) * 128;
    } else {
        Bt = B0;
        col0B = nb * 128;
    }

    // staging addresses (per-thread, fixed across K-iters except kk)
    const int rIn  = lane >> 2;             // 0..15 row-in-chunk
    const int kof  = 8 * (lane & 3);        // 0,8,16,24 (u16)
    const size_t aRow0 = (size_t)(row0 + 16 * wave       + rIn) * D + kof;
    const size_t aRow1 = (size_t)(row0 + 16 * (wave + 4) + rIn) * D + kof;
    const size_t bRow0 = (size_t)(col0B + 16 * wave       + rIn) * D + kof;
    const size_t bRow1 = (size_t)(col0B + 16 * (wave + 4) + rIn) * D + kof;
    u16* ldsA0 = &As[512 * wave + 8 * lane];
    u16* ldsA1 = &As[512 * (wave + 4) + 8 * lane];
    u16* ldsB0 = &Bs[512 * wave + 8 * lane];
    u16* ldsB1 = &Bs[512 * (wave + 4) + 8 * lane];

    // fragment read offsets (u16 units)
    const int aoff = (wr * 64 + ql) * 32 + hi * 8;
    const int boff = (wc * 64 + ql) * 32 + hi * 8;

    f16acc acc00 = zero16(), acc01 = zero16(), acc10 = zero16(), acc11 = zero16();

    for (int kk = 0; kk < D; kk += 32) {
        gload16(Ab + aRow0 + kk, ldsA0);
        gload16(Ab + aRow1 + kk, ldsA1);
        gload16(Bt + bRow0 + kk, ldsB0);
        gload16(Bt + bRow1 + kk, ldsB1);
        __syncthreads();
#pragma unroll
        for (int ks = 0; ks < 2; ++ks) {
            const bfrag a0 = *(const bfrag*)&As[aoff + ks * 16];
            const bfrag a1 = *(const bfrag*)&As[aoff + 32 * 32 + ks * 16];
            const bfrag b0 = *(const bfrag*)&Bs[boff + ks * 16];
            const bfrag b1 = *(const bfrag*)&Bs[boff + 32 * 32 + ks * 16];
            acc00 = MFMA(a0, b0, acc00);
            acc01 = MFMA(a0, b1, acc01);
            acc10 = MFMA(a1, b0, acc10);
            acc11 = MFMA(a1, b1, acc11);
        }
        __syncthreads();
    }

    // ---- epilogues ----
    f16acc accA[2][2];
    accA[0][0] = acc00; accA[0][1] = acc01; accA[1][0] = acc10; accA[1][1] = acc11;

    if (MODE == 0 && nb < 16) {
        u16* Dst = (nb < 8) ? Qb : Kb;
        const float sc = (nb < 8) ? SCALE_Q : 1.0f;
        const int m = ql >> 1;
        const bool ev = (ql & 1) == 0;
#pragma unroll
        for (int i = 0; i < 2; ++i)
#pragma unroll
        for (int j = 0; j < 2; ++j) {
            const int n = (nb & 7) * 128 + wc * 64 + j * 32 + ql;
            const int head = n >> 5;
            u16* hb = Dst + (size_t)head * S * HD;
#pragma unroll
            for (int r = 0; r < 16; ++r) {
                const int row = row0 + wr * 64 + i * 32 + 4 * hi + (r & 3) + 8 * (r >> 2);
                const float self = accA[i][j][r];
                const float part = __shfl_xor(self, 1);
                const float c = cosT[(row << 4) + m], s = sinT[(row << 4) + m];
                const float res = ev ? (self * c - part * s) : (part * s + self * c);
                hb[(size_t)row * HD + ql] = f2bf(res * sc);
            }
        }
    } else if (MODE == 0) {     // V: write V^T[n][s]
#pragma unroll
        for (int i = 0; i < 2; ++i)
#pragma unroll
        for (int j = 0; j < 2; ++j) {
            const int n = (nb & 7) * 128 + wc * 64 + j * 32 + ql;
            u16* cb = VT + (size_t)n * S;
#pragma unroll
            for (int q = 0; q < 4; ++q) {
                const int row = row0 + wr * 64 + i * 32 + 4 * hi + 8 * q;
                u16x4 res;
                res.x = f2bf(accA[i][j][4 * q + 0]);
                res.y = f2bf(accA[i][j][4 * q + 1]);
                res.z = f2bf(accA[i][j][4 * q + 2]);
                res.w = f2bf(accA[i][j][4 * q + 3]);
                *(u16x4*)&cb[row] = res;
            }
        }
    } else {                    // O-projection: f32 row-major
#pragma unroll
        for (int i = 0; i < 2; ++i)
#pragma unroll
        for (int j = 0; j < 2; ++j) {
            const int gcol = col0B + wc * 64 + j * 32 + ql;
#pragma unroll
            for (int r = 0; r < 16; ++r) {
                const int row = row0 + wr * 64 + i * 32 + 4 * hi + (r & 3) + 8 * (r >> 2);
                Of[(size_t)row * D + gcol] = accA[i][j][r];
            }
        }
    }
}

// ---------------- MFMA differential flash attention (unchanged core; bf16 AO out) ----------------
__global__ __launch_bounds__(256)
void attn_mfma(const u16* __restrict__ Qb, const u16* __restrict__ Kb,
               const u16* __restrict__ Vt, const float* __restrict__ lamPtr,
               const float* __restrict__ g, u16* __restrict__ AO) {
    const int h    = blockIdx.y;
    const int tid  = threadIdx.x;
    const int wave = tid >> 6;
    const int lane = tid & 63;
    const int hi   = lane >> 5;
    const int ql   = lane & 31;
    const int q0   = (blockIdx.x * 4 + wave) * 32;
    const float lam = *lamPtr;

    const u16* qp1 = Qb + ((size_t)(2 * h) * S + q0 + ql) * HD + 8 * hi;
    const u16* qp2 = qp1 + (size_t)S * HD;
    bfrag qf1[2], qf2[2];
    qf1[0] = *(const bfrag*)(qp1);      qf1[1] = *(const bfrag*)(qp1 + 16);
    qf2[0] = *(const bfrag*)(qp2);      qf2[1] = *(const bfrag*)(qp2 + 16);

    const u16* kp1 = Kb + ((size_t)(2 * h) * S + ql) * HD + 8 * hi;
    const u16* kp2 = kp1 + (size_t)S * HD;
    const u16* vp  = Vt + ((size_t)(h * 64) + ql) * S + 8 * hi;

    f16acc acc1[2], acc2[2];
    acc1[0] = zero16(); acc1[1] = zero16();
    acc2[0] = zero16(); acc2[1] = zero16();
    float m1 = -3.0e38f, m2 = -3.0e38f, l1 = 0.f, l2 = 0.f;

    bfrag k1c[2], k2c[2], vc[2][2];
#pragma unroll
    for (int s = 0; s < 2; ++s) {
        k1c[s] = *(const bfrag*)(kp1 + 16 * s);
        k2c[s] = *(const bfrag*)(kp2 + 16 * s);
#pragma unroll
        for (int dt = 0; dt < 2; ++dt)
            vc[s][dt] = *(const bfrag*)(vp + (size_t)dt * 32 * S + 16 * s);
    }

    for (int c = 0; c < 64; ++c) {
        const int cn = (c < 63) ? c + 1 : c;
        bfrag k1n[2], k2n[2], vn[2][2];
#pragma unroll
        for (int s = 0; s < 2; ++s) {
            k1n[s] = *(const bfrag*)(kp1 + (size_t)cn * 1024 + 16 * s);
            k2n[s] = *(const bfrag*)(kp2 + (size_t)cn * 1024 + 16 * s);
#pragma unroll
            for (int dt = 0; dt < 2; ++dt)
                vn[s][dt] = *(const bfrag*)(vp + (size_t)dt * 32 * S + (size_t)cn * 32 + 16 * s);
        }

        f16acc s1 = zero16(), s2 = zero16();
        s1 = MFMA(k1c[0], qf1[0], s1);  s1 = MFMA(k1c[1], qf1[1], s1);
        s2 = MFMA(k2c[0], qf2[0], s2);  s2 = MFMA(k2c[1], qf2[1], s2);

        float cm1 = s1[0], cm2 = s2[0];
#pragma unroll
        for (int r = 1; r < 16; ++r) { cm1 = fmaxf(cm1, s1[r]); cm2 = fmaxf(cm2, s2[r]); }
        cm1 = fmaxf(cm1, __shfl_xor(cm1, 32));
        cm2 = fmaxf(cm2, __shfl_xor(cm2, 32));
        if (__any((cm1 > m1 + 8.f) || (cm2 > m2 + 8.f))) {
            float nm1 = fmaxf(m1, cm1), nm2 = fmaxf(m2, cm2);
            float f1 = __expf(m1 - nm1), f2 = __expf(m2 - nm2);
#pragma unroll
            for (int dt = 0; dt < 2; ++dt)
#pragma unroll
                for (int r = 0; r < 16; ++r) { acc1[dt][r] *= f1; acc2[dt][r] *= f2; }
            l1 *= f1; l2 *= f2; m1 = nm1; m2 = nm2;
        }
        float e1[16], e2[16];
        float ls1 = 0.f, ls2 = 0.f;
#pragma unroll
        for (int r = 0; r < 16; ++r) {
            e1[r] = __expf(s1[r] - m1); ls1 += e1[r];
            e2[r] = __expf(s2[r] - m2); ls2 += e2[r];
        }
        ls1 += __shfl_xor(ls1, 32);
        ls2 += __shfl_xor(ls2, 32);
        l1 += ls1; l2 += ls2;

        u32 w1[8], w2[8];
#pragma unroll
        for (int j = 0; j < 8; ++j) {
            asm("v_cvt_pk_bf16_f32 %0, %1, %2" : "=v"(w1[j]) : "v"(e1[2 * j]), "v"(e1[2 * j + 1]));
            asm("v_cvt_pk_bf16_f32 %0, %1, %2" : "=v"(w2[j]) : "v"(e2[2 * j]), "v"(e2[2 * j + 1]));
        }
        asm("v_permlane32_swap_b32 %0, %1" : "+v"(w1[0]), "+v"(w1[2]));
        asm("v_permlane32_swap_b32 %0, %1" : "+v"(w1[1]), "+v"(w1[3]));
        asm("v_permlane32_swap_b32 %0, %1" : "+v"(w1[4]), "+v"(w1[6]));
        asm("v_permlane32_swap_b32 %0, %1" : "+v"(w1[5]), "+v"(w1[7]));
        asm("v_permlane32_swap_b32 %0, %1" : "+v"(w2[0]), "+v"(w2[2]));
        asm("v_permlane32_swap_b32 %0, %1" : "+v"(w2[1]), "+v"(w2[3]));
        asm("v_permlane32_swap_b32 %0, %1" : "+v"(w2[4]), "+v"(w2[6]));
        asm("v_permlane32_swap_b32 %0, %1" : "+v"(w2[5]), "+v"(w2[7]));
        uint4v t;
        bfrag p1[2], p2[2];
        t[0] = w1[0]; t[1] = w1[1]; t[2] = w1[2]; t[3] = w1[3];
        p1[0] = __builtin_bit_cast(bfrag, t);
        t[0] = w1[4]; t[1] = w1[5]; t[2] = w1[6]; t[3] = w1[7];
        p1[1] = __builtin_bit_cast(bfrag, t);
        t[0] = w2[0]; t[1] = w2[1]; t[2] = w2[2]; t[3] = w2[3];
        p2[0] = __builtin_bit_cast(bfrag, t);
        t[0] = w2[4]; t[1] = w2[5]; t[2] = w2[6]; t[3] = w2[7];
        p2[1] = __builtin_bit_cast(bfrag, t);

#pragma unroll
        for (int dt = 0; dt < 2; ++dt) {
            acc1[dt] = MFMA(vc[0][dt], p1[0], acc1[dt]);
            acc1[dt] = MFMA(vc[1][dt], p1[1], acc1[dt]);
            acc2[dt] = MFMA(vc[0][dt], p2[0], acc2[dt]);
            acc2[dt] = MFMA(vc[1][dt], p2[1], acc2[dt]);
        }

#pragma unroll
        for (int s = 0; s < 2; ++s) {
            k1c[s] = k1n[s]; k2c[s] = k2n[s];
#pragma unroll
            for (int dt = 0; dt < 2; ++dt) vc[s][dt] = vn[s][dt];
        }
    }

    const float inv1 = 1.0f / l1, inv2 = 1.0f / l2;
    float o_[2][16];
    float ss = 0.f;
#pragma unroll
    for (int dt = 0; dt < 2; ++dt)
#pragma unroll
        for (int r = 0; r < 16; ++r) {
            float o = acc1[dt][r] * inv1 - lam * (acc2[dt][r] * inv2);
            o_[dt][r] = o;
            ss += o * o;
        }
    ss += __shfl_xor(ss, 32);
    const float rs = rsqrtf(ss * (1.0f / 64.0f) + 1e-5f);

    u16* aorow = AO + (size_t)(q0 + ql) * D + h * 64;
#pragma unroll
    for (int dt = 0; dt < 2; ++dt)
#pragma unroll
        for (int G = 0; G < 4; ++G) {
            const int dbase = dt * 32 + G * 8 + hi * 4;
            const float4 gv = *(const float4*)&g[dbase];
            u16x4 res;
            res.x = f2bf(o_[dt][4 * G + 0] * rs * gv.x * ONE_MINUS_LI);
            res.y = f2bf(o_[dt][4 * G + 1] * rs * gv.y * ONE_MINUS_LI);
            res.z = f2bf(o_[dt][4 * G + 2] * rs * gv.z * ONE_MINUS_LI);
            res.w = f2bf(o_[dt][4 * G + 3] * rs * gv.w * ONE_MINUS_LI);
            *(u16x4*)&aorow[dbase] = res;
        }
}

// ---------------- launch ----------------
extern "C" void kernel_launch(void* const* d_in, const int* in_sizes, int n_in,
                              void* d_out, int out_size, void* d_ws, size_t ws_size,
                              hipStream_t stream) {
    const float* x   = (const float*)d_in[0];
    const float* Wq  = (const float*)d_in[1];
    const float* Wk  = (const float*)d_in[2];
    const float* Wv  = (const float*)d_in[3];
    const float* Wo  = (const float*)d_in[4];
    const float* lq1 = (const float*)d_in[5];
    const float* lk1 = (const float*)d_in[6];
    const float* lq2 = (const float*)d_in[7];
    const float* lk2 = (const float*)d_in[8];
    const float* g   = (const float*)d_in[9];
    float* out = (float*)d_out;

    char* ws = (char*)d_ws;
    float* cosT = (float*)(ws);                                // 128 KB
    float* sinT = (float*)(ws + 131072);                       // 128 KB
    float* lam  = (float*)(ws + 262144);                       // 256 B
    char*  b    = ws + 262400;
    u16*   Qb   = (u16*)(b);                                   // 4 MB
    u16*   Kb   = (u16*)(b + 4194304);                         // 4 MB
    u16*   VT   = (u16*)(b + 8388608);                         // 4 MB
    u16*   AO   = (u16*)(b + 12582912);                        // 4 MB (bf16)
    u16*   xb   = (u16*)(b + 16777216);                        // 4 MB
    u16*   WqT  = (u16*)(b + 20971520);                        // 2 MB
    u16*   WkT  = (u16*)(b + 23068672);                        // 2 MB
    u16*   WvT  = (u16*)(b + 25165824);                        // 2 MB
    u16*   WoT  = (u16*)(b + 27262976);                        // 2 MB

    prep_kernel<<<128, 256, 0, stream>>>(lq1, lk1, lq2, lk2, cosT, sinT, lam);
    convert_kernel<<<dim3(4096, 5), 256, 0, stream>>>(x, Wq, Wk, Wv, Wo,
                                                      xb, WqT, WkT, WvT, WoT);

    mm_kernel<0><<<dim3(24, 16), 256, 0, stream>>>(xb, WqT, WkT, WvT, cosT, sinT,
                                                   Qb, Kb, VT, nullptr);

    attn_mfma<<<dim3(16, NH), 256, 0, stream>>>(Qb, Kb, VT, lam, g, AO);

    mm_kernel<1><<<dim3(8, 16), 256, 0, stream>>>(AO, WoT, nullptr, nullptr, cosT, sinT,
                                                  nullptr, nullptr, nullptr, out);
}

// Round 6
// 143.665 us; speedup vs baseline: 22.8465x; 1.0598x over previous
//
#include <hip/hip_runtime.h>
#include <math.h>

#define S 2048
#define D 1024
#define NH 16
#define HD 32
#define HD2 64

static constexpr float SCALE_Q       = 0.17677669529663687f;   // 32^-0.5
static constexpr float SCALE_Q_EXP2  = 0.17677669529663687f * 1.4426950408889634f; // *log2(e)
static constexpr float LAMBDA_INIT_F = 0.78360576653162450f;   // 0.8 - 0.6*exp(-3.6)
static constexpr float ONE_MINUS_LI  = 0.21639423346837553f;
static constexpr float DEFER_THR_L2  = 11.5415604f;            // 8 nats in base-2

typedef unsigned short u16;
typedef unsigned int   u32;
typedef __attribute__((ext_vector_type(4)))  unsigned short u16x4;
typedef __attribute__((ext_vector_type(8)))  short          bfrag;   // 8 bf16 = 4 VGPR
typedef __attribute__((ext_vector_type(16))) float          f16acc;  // MFMA 32x32 accumulator
typedef __attribute__((ext_vector_type(4)))  unsigned int   uint4v;

__device__ __forceinline__ u16 f2bf(float f) {                 // RNE f32->bf16
    u32 u = __builtin_bit_cast(u32, f);
    return (u16)((u + 0x7FFFu + ((u >> 16) & 1u)) >> 16);
}
__device__ __forceinline__ f16acc zero16() {
    f16acc z;
#pragma unroll
    for (int i = 0; i < 16; ++i) z[i] = 0.f;
    return z;
}
#define MFMA(a, b, c) __builtin_amdgcn_mfma_f32_32x32x16_bf16(a, b, c, 0, 0, 0)

__device__ __forceinline__ void gload16(const u16* src, u16* lds) {
    __builtin_amdgcn_global_load_lds((const __attribute__((address_space(1))) void*)src,
                                     (__attribute__((address_space(3))) void*)lds, 16, 0, 0);
}

// ---------------- prep: trig tables (bit-matching the f32 numpy/jax pipeline) ----------------
__global__ void prep_kernel(const float* __restrict__ lq1, const float* __restrict__ lk1,
                            const float* __restrict__ lq2, const float* __restrict__ lk2,
                            float* __restrict__ cosT, float* __restrict__ sinT,
                            float* __restrict__ lamOut) {
    int idx = blockIdx.x * blockDim.x + threadIdx.x;
    if (idx < S * 16) {
        int p = idx >> 4;
        int m = idx & 15;
        const double base = (double)1.0e-4f;
        float pf   = (float)pow(base, (double)m * (1.0 / 16.0));  // == powf(1e-4f, m/16), CR
        float freq = 1.0f / pf;                                   // f32 division
        float angf = (float)p * freq;                             // exact f32 multiply
        double a = (double)angf;
        cosT[idx] = (float)cos(a);
        sinT[idx] = (float)sin(a);
    }
    if (blockIdx.x == 0 && threadIdx.x == 0) {
        float s1 = 0.f, s2 = 0.f;
        for (int i = 0; i < HD; ++i) {
            s1 += lq1[i] * lk1[i];
            s2 += lq2[i] * lk2[i];
        }
        *lamOut = expf(s1) - expf(s2) + LAMBDA_INIT_F;
    }
}

// ---------------- convert: x -> bf16; W -> bf16 transposed [n][k] ----------------
__global__ __launch_bounds__(256)
void convert_kernel(const float* __restrict__ x,  const float* __restrict__ Wq,
                    const float* __restrict__ Wk, const float* __restrict__ Wv,
                    const float* __restrict__ Wo,
                    u16* __restrict__ xb,  u16* __restrict__ WqT, u16* __restrict__ WkT,
                    u16* __restrict__ WvT, u16* __restrict__ WoT) {
    const int z = blockIdx.y;
    const int i = blockIdx.x * 256 + threadIdx.x;
    if (z == 0) {
        if (i < (S * D) / 4) {
            const float4 v = *(const float4*)&x[(size_t)i * 4];
            u16x4 r; r.x = f2bf(v.x); r.y = f2bf(v.y); r.z = f2bf(v.z); r.w = f2bf(v.w);
            *(u16x4*)&xb[(size_t)i * 4] = r;
        }
    } else {
        if (i < D * D) {
            const int k = i >> 10, n = i & 1023;
            const float* W = (z == 1) ? Wq : (z == 2) ? Wk : (z == 3) ? Wv : Wo;
            u16* T = (z == 1) ? WqT : (z == 2) ? WkT : (z == 3) ? WvT : WoT;
            T[(size_t)n * D + k] = f2bf(W[i]);
        }
    }
}

// ---------------- bf16 MFMA GEMM, 128x128 tile, BK=32, 4 waves (m97 structure) ----------------
template<int MODE>
__global__ __launch_bounds__(256)
void mm_kernel(const u16* __restrict__ Ab, const u16* __restrict__ B0,
               const u16* __restrict__ B1, const u16* __restrict__ B2,
               const float* __restrict__ cosT, const float* __restrict__ sinT,
               u16* __restrict__ Qb, u16* __restrict__ Kb, u16* __restrict__ VT,
               float* __restrict__ Of) {
    __shared__ u16 As[128 * 32];
    __shared__ u16 Bs[128 * 32];

    const int nb   = blockIdx.x;
    const int row0 = blockIdx.y * 128;
    const int tid  = threadIdx.x;
    const int wave = tid >> 6;
    const int lane = tid & 63;
    const int ql   = lane & 31;
    const int hi   = lane >> 5;
    const int wr   = wave >> 1;
    const int wc   = wave & 1;

    const u16* Bt;
    int col0B;
    if (MODE == 0) {
        Bt = (nb < 8) ? B0 : (nb < 16) ? B1 : B2;
        col0B = (nb & 7) * 128;
    } else {
        Bt = B0;
        col0B = nb * 128;
    }

    const int rIn  = lane >> 2;
    const int kof  = 8 * (lane & 3);
    const size_t aRow0 = (size_t)(row0 + 16 * wave       + rIn) * D + kof;
    const size_t aRow1 = (size_t)(row0 + 16 * (wave + 4) + rIn) * D + kof;
    const size_t bRow0 = (size_t)(col0B + 16 * wave       + rIn) * D + kof;
    const size_t bRow1 = (size_t)(col0B + 16 * (wave + 4) + rIn) * D + kof;
    u16* ldsA0 = &As[512 * wave + 8 * lane];
    u16* ldsA1 = &As[512 * (wave + 4) + 8 * lane];
    u16* ldsB0 = &Bs[512 * wave + 8 * lane];
    u16* ldsB1 = &Bs[512 * (wave + 4) + 8 * lane];

    const int aoff = (wr * 64 + ql) * 32 + hi * 8;
    const int boff = (wc * 64 + ql) * 32 + hi * 8;

    f16acc acc00 = zero16(), acc01 = zero16(), acc10 = zero16(), acc11 = zero16();

    for (int kk = 0; kk < D; kk += 32) {
        gload16(Ab + aRow0 + kk, ldsA0);
        gload16(Ab + aRow1 + kk, ldsA1);
        gload16(Bt + bRow0 + kk, ldsB0);
        gload16(Bt + bRow1 + kk, ldsB1);
        __syncthreads();
#pragma unroll
        for (int ks = 0; ks < 2; ++ks) {
            const bfrag a0 = *(const bfrag*)&As[aoff + ks * 16];
            const bfrag a1 = *(const bfrag*)&As[aoff + 32 * 32 + ks * 16];
            const bfrag b0 = *(const bfrag*)&Bs[boff + ks * 16];
            const bfrag b1 = *(const bfrag*)&Bs[boff + 32 * 32 + ks * 16];
            acc00 = MFMA(a0, b0, acc00);
            acc01 = MFMA(a0, b1, acc01);
            acc10 = MFMA(a1, b0, acc10);
            acc11 = MFMA(a1, b1, acc11);
        }
        __syncthreads();
    }

    f16acc accA[2][2];
    accA[0][0] = acc00; accA[0][1] = acc01; accA[1][0] = acc10; accA[1][1] = acc11;

    if (MODE == 0 && nb < 16) {
        u16* Dst = (nb < 8) ? Qb : Kb;
        const float sc = (nb < 8) ? SCALE_Q_EXP2 : 1.0f;   // Q pre-scaled into exp2 domain
        const int m = ql >> 1;
        const bool ev = (ql & 1) == 0;
#pragma unroll
        for (int i = 0; i < 2; ++i)
#pragma unroll
        for (int j = 0; j < 2; ++j) {
            const int n = (nb & 7) * 128 + wc * 64 + j * 32 + ql;
            const int head = n >> 5;
            u16* hb = Dst + (size_t)head * S * HD;
#pragma unroll
            for (int r = 0; r < 16; ++r) {
                const int row = row0 + wr * 64 + i * 32 + 4 * hi + (r & 3) + 8 * (r >> 2);
                const float self = accA[i][j][r];
                const float part = __shfl_xor(self, 1);
                const float c = cosT[(row << 4) + m], s = sinT[(row << 4) + m];
                const float res = ev ? (self * c - part * s) : (part * s + self * c);
                hb[(size_t)row * HD + ql] = f2bf(res * sc);
            }
        }
    } else if (MODE == 0) {
#pragma unroll
        for (int i = 0; i < 2; ++i)
#pragma unroll
        for (int j = 0; j < 2; ++j) {
            const int n = (nb & 7) * 128 + wc * 64 + j * 32 + ql;
            u16* cb = VT + (size_t)n * S;
#pragma unroll
            for (int q = 0; q < 4; ++q) {
                const int row = row0 + wr * 64 + i * 32 + 4 * hi + 8 * q;
                u16x4 res;
                res.x = f2bf(accA[i][j][4 * q + 0]);
                res.y = f2bf(accA[i][j][4 * q + 1]);
                res.z = f2bf(accA[i][j][4 * q + 2]);
                res.w = f2bf(accA[i][j][4 * q + 3]);
                *(u16x4*)&cb[row] = res;
            }
        }
    } else {
#pragma unroll
        for (int i = 0; i < 2; ++i)
#pragma unroll
        for (int j = 0; j < 2; ++j) {
            const int gcol = col0B + wc * 64 + j * 32 + ql;
#pragma unroll
            for (int r = 0; r < 16; ++r) {
                const int row = row0 + wr * 64 + i * 32 + 4 * hi + (r & 3) + 8 * (r >> 2);
                Of[(size_t)row * D + gcol] = accA[i][j][r];
            }
        }
    }
}

// ---------------- MFMA differential flash attention, in-block KV-split x2 ----------------
// block 512 = 8 waves: 4 q-tiles x 2 kv-halves. exp2-domain softmax (Q pre-scaled by log2e).
// LDS merge of the two halves' (m, l, acc); epilogue (diff, RMS, *g) in half-0 waves.
__global__ __launch_bounds__(512)
void attn_mfma(const u16* __restrict__ Qb, const u16* __restrict__ Kb,
               const u16* __restrict__ Vt, const float* __restrict__ lamPtr,
               const float* __restrict__ g, u16* __restrict__ AO) {
    const int h    = blockIdx.y;
    const int tid  = threadIdx.x;
    const int wave = tid >> 6;
    const int lane = tid & 63;
    const int hi   = lane >> 5;
    const int ql   = lane & 31;
    const int t    = wave >> 1;          // q-tile in block
    const int wv   = wave & 1;           // kv-half
    const int q0   = (blockIdx.x * 4 + t) * 32;
    const int cbase = wv * 32;           // first kv-chunk (32 keys each)
    const float lam = *lamPtr;

    __shared__ float CMB[4][64][69];     // [tile][lane][68 used] merge buffer (stride 69: conflict-free)

    const u16* qp1 = Qb + ((size_t)(2 * h) * S + q0 + ql) * HD + 8 * hi;
    const u16* qp2 = qp1 + (size_t)S * HD;
    bfrag qf1[2], qf2[2];
    qf1[0] = *(const bfrag*)(qp1);      qf1[1] = *(const bfrag*)(qp1 + 16);
    qf2[0] = *(const bfrag*)(qp2);      qf2[1] = *(const bfrag*)(qp2 + 16);

    const u16* kp1 = Kb + ((size_t)(2 * h) * S + ql) * HD + 8 * hi;
    const u16* kp2 = kp1 + (size_t)S * HD;
    const u16* vp  = Vt + ((size_t)(h * 64) + ql) * S + 8 * hi;

    f16acc acc1[2], acc2[2];
    acc1[0] = zero16(); acc1[1] = zero16();
    acc2[0] = zero16(); acc2[1] = zero16();
    float m1 = -3.0e38f, m2 = -3.0e38f, l1 = 0.f, l2 = 0.f;

    auto pload = [&](bfrag (&k1)[2], bfrag (&k2)[2], bfrag (&vv)[2][2], int c) {
#pragma unroll
        for (int s = 0; s < 2; ++s) {
            k1[s] = *(const bfrag*)(kp1 + (size_t)c * 1024 + 16 * s);
            k2[s] = *(const bfrag*)(kp2 + (size_t)c * 1024 + 16 * s);
#pragma unroll
            for (int dt = 0; dt < 2; ++dt)
                vv[s][dt] = *(const bfrag*)(vp + (size_t)dt * 32 * S + (size_t)c * 32 + 16 * s);
        }
    };

    auto body = [&](bfrag (&k1)[2], bfrag (&k2)[2], bfrag (&vv)[2][2]) {
        f16acc s1 = zero16(), s2 = zero16();
        __builtin_amdgcn_s_setprio(1);
        s1 = MFMA(k1[0], qf1[0], s1);  s1 = MFMA(k1[1], qf1[1], s1);
        s2 = MFMA(k2[0], qf2[0], s2);  s2 = MFMA(k2[1], qf2[1], s2);
        __builtin_amdgcn_s_setprio(0);

        // tree max over 16 regs (depth 4), then cross-half via lane^32
        float x1[8], x2[8];
#pragma unroll
        for (int j = 0; j < 8; ++j) { x1[j] = fmaxf(s1[2 * j], s1[2 * j + 1]);
                                      x2[j] = fmaxf(s2[2 * j], s2[2 * j + 1]); }
#pragma unroll
        for (int j = 0; j < 4; ++j) { x1[j] = fmaxf(x1[j], x1[j + 4]);
                                      x2[j] = fmaxf(x2[j], x2[j + 4]); }
        float cm1 = fmaxf(fmaxf(x1[0], x1[1]), fmaxf(x1[2], x1[3]));
        float cm2 = fmaxf(fmaxf(x2[0], x2[1]), fmaxf(x2[2], x2[3]));
        cm1 = fmaxf(cm1, __shfl_xor(cm1, 32));
        cm2 = fmaxf(cm2, __shfl_xor(cm2, 32));
        if (__any((cm1 > m1 + DEFER_THR_L2) || (cm2 > m2 + DEFER_THR_L2))) {
            float nm1 = fmaxf(m1, cm1), nm2 = fmaxf(m2, cm2);
            float f1 = exp2f(m1 - nm1), f2 = exp2f(m2 - nm2);
#pragma unroll
            for (int dt = 0; dt < 2; ++dt)
#pragma unroll
                for (int r = 0; r < 16; ++r) { acc1[dt][r] *= f1; acc2[dt][r] *= f2; }
            l1 *= f1; l2 *= f2; m1 = nm1; m2 = nm2;
        }
        float ls1 = 0.f, ls2 = 0.f;
#pragma unroll
        for (int r = 0; r < 16; ++r) {       // in-place exp2 (scores already log2-scaled)
            s1[r] = exp2f(s1[r] - m1); ls1 += s1[r];
            s2[r] = exp2f(s2[r] - m2); ls2 += s2[r];
        }
        ls1 += __shfl_xor(ls1, 32);
        ls2 += __shfl_xor(ls2, 32);
        l1 += ls1; l2 += ls2;

        u32 w1[8], w2[8];
#pragma unroll
        for (int j = 0; j < 8; ++j) {
            asm("v_cvt_pk_bf16_f32 %0, %1, %2" : "=v"(w1[j]) : "v"(s1[2 * j]), "v"(s1[2 * j + 1]));
            asm("v_cvt_pk_bf16_f32 %0, %1, %2" : "=v"(w2[j]) : "v"(s2[2 * j]), "v"(s2[2 * j + 1]));
        }
        asm("v_permlane32_swap_b32 %0, %1" : "+v"(w1[0]), "+v"(w1[2]));
        asm("v_permlane32_swap_b32 %0, %1" : "+v"(w1[1]), "+v"(w1[3]));
        asm("v_permlane32_swap_b32 %0, %1" : "+v"(w1[4]), "+v"(w1[6]));
        asm("v_permlane32_swap_b32 %0, %1" : "+v"(w1[5]), "+v"(w1[7]));
        asm("v_permlane32_swap_b32 %0, %1" : "+v"(w2[0]), "+v"(w2[2]));
        asm("v_permlane32_swap_b32 %0, %1" : "+v"(w2[1]), "+v"(w2[3]));
        asm("v_permlane32_swap_b32 %0, %1" : "+v"(w2[4]), "+v"(w2[6]));
        asm("v_permlane32_swap_b32 %0, %1" : "+v"(w2[5]), "+v"(w2[7]));
        uint4v u;
        bfrag p1[2], p2[2];
        u[0] = w1[0]; u[1] = w1[1]; u[2] = w1[2]; u[3] = w1[3];
        p1[0] = __builtin_bit_cast(bfrag, u);
        u[0] = w1[4]; u[1] = w1[5]; u[2] = w1[6]; u[3] = w1[7];
        p1[1] = __builtin_bit_cast(bfrag, u);
        u[0] = w2[0]; u[1] = w2[1]; u[2] = w2[2]; u[3] = w2[3];
        p2[0] = __builtin_bit_cast(bfrag, u);
        u[0] = w2[4]; u[1] = w2[5]; u[2] = w2[6]; u[3] = w2[7];
        p2[1] = __builtin_bit_cast(bfrag, u);

        __builtin_amdgcn_s_setprio(1);
#pragma unroll
        for (int dt = 0; dt < 2; ++dt) {
            acc1[dt] = MFMA(vv[0][dt], p1[0], acc1[dt]);
            acc1[dt] = MFMA(vv[1][dt], p1[1], acc1[dt]);
            acc2[dt] = MFMA(vv[0][dt], p2[0], acc2[dt]);
            acc2[dt] = MFMA(vv[1][dt], p2[1], acc2[dt]);
        }
        __builtin_amdgcn_s_setprio(0);
    };

    // ping-pong named buffers, explicit 2x unroll (no rotate movs)
    bfrag kA1[2], kA2[2], vA[2][2];
    bfrag kB1[2], kB2[2], vB[2][2];
    pload(kA1, kA2, vA, cbase);
    for (int i = 0; i < 32; i += 2) {
        pload(kB1, kB2, vB, cbase + i + 1);
        body(kA1, kA2, vA);
        const int c2 = (i + 2 < 32) ? cbase + i + 2 : cbase + 31;
        pload(kA1, kA2, vA, c2);
        body(kB1, kB2, vB);
    }

    // ---- merge the two kv-halves through LDS ----
    if (wv == 1) {
        float* c0 = &CMB[t][lane][0];
#pragma unroll
        for (int dt = 0; dt < 2; ++dt)
#pragma unroll
            for (int r = 0; r < 16; ++r) {
                c0[dt * 16 + r]      = acc1[dt][r];
                c0[32 + dt * 16 + r] = acc2[dt][r];
            }
        c0[64] = m1; c0[65] = l1; c0[66] = m2; c0[67] = l2;
    }
    __syncthreads();
    if (wv == 0) {
        const float* c0 = &CMB[t][lane][0];
        const float mb1 = c0[64], lb1 = c0[65], mb2 = c0[66], lb2 = c0[67];
        const float nm1 = fmaxf(m1, mb1), nm2 = fmaxf(m2, mb2);
        const float fa1 = exp2f(m1 - nm1), fb1 = exp2f(mb1 - nm1);
        const float fa2 = exp2f(m2 - nm2), fb2 = exp2f(mb2 - nm2);
        l1 = l1 * fa1 + lb1 * fb1;
        l2 = l2 * fa2 + lb2 * fb2;
#pragma unroll
        for (int dt = 0; dt < 2; ++dt)
#pragma unroll
            for (int r = 0; r < 16; ++r) {
                acc1[dt][r] = acc1[dt][r] * fa1 + c0[dt * 16 + r] * fb1;
                acc2[dt][r] = acc2[dt][r] * fa2 + c0[32 + dt * 16 + r] * fb2;
            }

        const float inv1 = 1.0f / l1, inv2 = 1.0f / l2;
        float o_[2][16];
        float ss = 0.f;
#pragma unroll
        for (int dt = 0; dt < 2; ++dt)
#pragma unroll
            for (int r = 0; r < 16; ++r) {
                float o = acc1[dt][r] * inv1 - lam * (acc2[dt][r] * inv2);
                o_[dt][r] = o;
                ss += o * o;
            }
        ss += __shfl_xor(ss, 32);
        const float rs = rsqrtf(ss * (1.0f / 64.0f) + 1e-5f);

        u16* aorow = AO + (size_t)(q0 + ql) * D + h * 64;
#pragma unroll
        for (int dt = 0; dt < 2; ++dt)
#pragma unroll
            for (int G = 0; G < 4; ++G) {
                const int dbase = dt * 32 + G * 8 + hi * 4;
                const float4 gv = *(const float4*)&g[dbase];
                u16x4 res;
                res.x = f2bf(o_[dt][4 * G + 0] * rs * gv.x * ONE_MINUS_LI);
                res.y = f2bf(o_[dt][4 * G + 1] * rs * gv.y * ONE_MINUS_LI);
                res.z = f2bf(o_[dt][4 * G + 2] * rs * gv.z * ONE_MINUS_LI);
                res.w = f2bf(o_[dt][4 * G + 3] * rs * gv.w * ONE_MINUS_LI);
                *(u16x4*)&aorow[dbase] = res;
            }
    }
}

// ---------------- launch ----------------
extern "C" void kernel_launch(void* const* d_in, const int* in_sizes, int n_in,
                              void* d_out, int out_size, void* d_ws, size_t ws_size,
                              hipStream_t stream) {
    const float* x   = (const float*)d_in[0];
    const float* Wq  = (const float*)d_in[1];
    const float* Wk  = (const float*)d_in[2];
    const float* Wv  = (const float*)d_in[3];
    const float* Wo  = (const float*)d_in[4];
    const float* lq1 = (const float*)d_in[5];
    const float* lk1 = (const float*)d_in[6];
    const float* lq2 = (const float*)d_in[7];
    const float* lk2 = (const float*)d_in[8];
    const float* g   = (const float*)d_in[9];
    float* out = (float*)d_out;

    char* ws = (char*)d_ws;
    float* cosT = (float*)(ws);                                // 128 KB
    float* sinT = (float*)(ws + 131072);                       // 128 KB
    float* lam  = (float*)(ws + 262144);                       // 256 B
    char*  b    = ws + 262400;
    u16*   Qb   = (u16*)(b);                                   // 4 MB
    u16*   Kb   = (u16*)(b + 4194304);                         // 4 MB
    u16*   VT   = (u16*)(b + 8388608);                         // 4 MB
    u16*   AO   = (u16*)(b + 12582912);                        // 4 MB (bf16)
    u16*   xb   = (u16*)(b + 16777216);                        // 4 MB
    u16*   WqT  = (u16*)(b + 20971520);                        // 2 MB
    u16*   WkT  = (u16*)(b + 23068672);                        // 2 MB
    u16*   WvT  = (u16*)(b + 25165824);                        // 2 MB
    u16*   WoT  = (u16*)(b + 27262976);                        // 2 MB

    prep_kernel<<<128, 256, 0, stream>>>(lq1, lk1, lq2, lk2, cosT, sinT, lam);
    convert_kernel<<<dim3(4096, 5), 256, 0, stream>>>(x, Wq, Wk, Wv, Wo,
                                                      xb, WqT, WkT, WvT, WoT);

    mm_kernel<0><<<dim3(24, 16), 256, 0, stream>>>(xb, WqT, WkT, WvT, cosT, sinT,
                                                   Qb, Kb, VT, nullptr);

    attn_mfma<<<dim3(16, NH), 512, 0, stream>>>(Qb, Kb, VT, lam, g, AO);

    mm_kernel<1><<<dim3(8, 16), 256, 0, stream>>>(AO, WoT, nullptr, nullptr, cosT, sinT,
                                                  nullptr, nullptr, nullptr, out);
}